// Round 1
// baseline (543.514 us; speedup 1.0000x reference)
//
#include <hip/hip_runtime.h>
#include <hip/hip_bf16.h>

#define NEG_SLOPE 0.2f

// ---------------- CSR build ----------------

__global__ void k_init_counts(int* counts, int n) {
    int i = blockIdx.x * blockDim.x + threadIdx.x;
    if (i < n) counts[i] = 1;  // self loop contributes 1 to every node
}

__global__ void k_hist(const int* __restrict__ ei, int E, int* counts) {
    int i = blockIdx.x * blockDim.x + threadIdx.x;
    if (i < E) atomicAdd(&counts[ei[E + i]], 1);  // dst row = ei[E..2E)
}

// single-block exclusive scan over counts -> rowptr[0..n]
__global__ void k_scan(const int* __restrict__ counts, int* __restrict__ rowptr, int n) {
    __shared__ int sm[1024];
    __shared__ int carry_s;
    int t = threadIdx.x;
    if (t == 0) { carry_s = 0; rowptr[0] = 0; }
    __syncthreads();
    for (int base = 0; base < n; base += 1024) {
        int v = (base + t < n) ? counts[base + t] : 0;
        __syncthreads();          // protect sm reuse
        sm[t] = v;
        __syncthreads();
        for (int off = 1; off < 1024; off <<= 1) {
            int x = (t >= off) ? sm[t - off] : 0;
            __syncthreads();
            sm[t] += x;
            __syncthreads();
        }
        int carry = carry_s;
        if (base + t < n) rowptr[base + t + 1] = carry + sm[t];
        int total = sm[1023];
        __syncthreads();
        if (t == 0) carry_s = carry + total;
        __syncthreads();
    }
}

__global__ void k_scatter(const int* __restrict__ ei, int E, int n,
                          const int* __restrict__ rowptr, int* __restrict__ cursor,
                          int* __restrict__ csrc) {
    int i = blockIdx.x * blockDim.x + threadIdx.x;
    int tot = E + n;
    if (i >= tot) return;
    int s, d;
    if (i < E) { s = ei[i]; d = ei[E + i]; } else { s = i - E; d = s; }
    int pos = rowptr[d] + atomicAdd(&cursor[d], 1);
    csrc[pos] = s;
}

// ---------------- f32 tiled GEMM: C[M,NC] = A[M,K] @ B[K,NC] ----------------
// BM=BN=64, BK=16, 256 threads, 4x4 microtile.

__global__ __launch_bounds__(256) void k_gemm(const float* __restrict__ A,
                                              const float* __restrict__ B,
                                              float* __restrict__ C,
                                              int M, int K, int NC) {
    __shared__ float As[16][68];   // [k][m], padded stride 68 (16B-aligned rows)
    __shared__ float Bs[16][64];   // [k][n]
    int tid = threadIdx.x;
    int tr = tid >> 4, tc = tid & 15;
    int bm = blockIdx.x * 64, bn = blockIdx.y * 64;
    float acc[4][4] = {};
    int ar = tid >> 2, ak = (tid & 3) << 2;   // A: row 0..63, k-chunk of 4
    int br = tid >> 4, bc = (tid & 15) << 2;  // B: row 0..15, col-chunk of 4
    for (int k0 = 0; k0 < K; k0 += 16) {
        float4 av = make_float4(0.f, 0.f, 0.f, 0.f);
        if (bm + ar < M)
            av = *reinterpret_cast<const float4*>(A + (size_t)(bm + ar) * K + k0 + ak);
        As[ak + 0][ar] = av.x; As[ak + 1][ar] = av.y;
        As[ak + 2][ar] = av.z; As[ak + 3][ar] = av.w;
        float4 bv = *reinterpret_cast<const float4*>(B + (size_t)(k0 + br) * NC + bn + bc);
        *reinterpret_cast<float4*>(&Bs[br][bc]) = bv;
        __syncthreads();
#pragma unroll
        for (int kk = 0; kk < 16; ++kk) {
            float4 a4 = *reinterpret_cast<const float4*>(&As[kk][tr << 2]);
            float4 b4 = *reinterpret_cast<const float4*>(&Bs[kk][tc << 2]);
            float af[4] = {a4.x, a4.y, a4.z, a4.w};
            float bf[4] = {b4.x, b4.y, b4.z, b4.w};
#pragma unroll
            for (int i = 0; i < 4; ++i)
#pragma unroll
                for (int j = 0; j < 4; ++j) acc[i][j] += af[i] * bf[j];
        }
        __syncthreads();
    }
#pragma unroll
    for (int i = 0; i < 4; ++i) {
        int r = bm + (tr << 2) + i;
        if (r < M) {
#pragma unroll
            for (int j = 0; j < 4; ++j)
                C[(size_t)r * NC + bn + (tc << 2) + j] = acc[i][j];
        }
    }
}

// ---------------- attention coefficients: als/ald [N,8] ----------------
// one wave per node; lane covers channels 4l..4l+3, head = l>>3

__global__ __launch_bounds__(256) void k_attn(const float* __restrict__ xl,
                                              const float* __restrict__ as_,
                                              const float* __restrict__ ad_,
                                              float* __restrict__ als,
                                              float* __restrict__ ald, int n) {
    int node = (int)(((size_t)blockIdx.x * blockDim.x + threadIdx.x) >> 6);
    if (node >= n) return;
    int lane = threadIdx.x & 63;
    float4 xv = *reinterpret_cast<const float4*>(xl + (size_t)node * 256 + (lane << 2));
    float4 sv = *reinterpret_cast<const float4*>(as_ + (lane << 2));
    float4 dv = *reinterpret_cast<const float4*>(ad_ + (lane << 2));
    float ps = xv.x * sv.x + xv.y * sv.y + xv.z * sv.z + xv.w * sv.w;
    float pd = xv.x * dv.x + xv.y * dv.y + xv.z * dv.z + xv.w * dv.w;
#pragma unroll
    for (int off = 1; off < 8; off <<= 1) {
        ps += __shfl_xor(ps, off);
        pd += __shfl_xor(pd, off);
    }
    if ((lane & 7) == 0) {
        als[node * 8 + (lane >> 3)] = ps;
        ald[node * 8 + (lane >> 3)] = pd;
    }
}

// ---------------- per-node softmax + aggregation (layers 0-2, ELU fused) ----------------

__global__ __launch_bounds__(256) void k_agg(const float* __restrict__ xl,
                                             const float* __restrict__ als,
                                             const float* __restrict__ ald,
                                             const int* __restrict__ rowptr,
                                             const int* __restrict__ csrc,
                                             const float* __restrict__ bias,
                                             float* __restrict__ hout, int n) {
    int node = (int)(((size_t)blockIdx.x * blockDim.x + threadIdx.x) >> 6);
    if (node >= n) return;
    int lane = threadIdx.x & 63;
    int beg = rowptr[node];
    int deg = rowptr[node + 1] - beg;

    // sweep 1: online softmax stats, 8 edges in parallel (lane = 8*edge_slot + head)
    int h1 = lane & 7;
    float aldv = ald[node * 8 + h1];
    float m = -1e30f, s = 0.f;
    for (int ee = lane >> 3; ee < deg; ee += 8) {
        int sidx = csrc[beg + ee];
        float e = als[sidx * 8 + h1] + aldv;
        e = e > 0.f ? e : NEG_SLOPE * e;
        float mn = fmaxf(m, e);
        s = s * __expf(m - mn) + __expf(e - mn);
        m = mn;
    }
#pragma unroll
    for (int off = 8; off < 64; off <<= 1) {
        float m2 = __shfl_xor(m, off);
        float s2 = __shfl_xor(s, off);
        float mn = fmaxf(m, m2);
        s = s * __expf(m - mn) + s2 * __expf(m2 - mn);
        m = mn;
    }
    // sweep 2 mapping: lane covers channels 4l..4l+3, head h2 = l>>3.
    int h2 = lane >> 3;
    float m_h = __shfl(m, h2);          // lane h2 holds head h2's stats
    float inv_s = 1.f / (__shfl(s, h2) + 1e-16f);
    float aldv2 = ald[node * 8 + h2];
    float4 acc = make_float4(0.f, 0.f, 0.f, 0.f);
    for (int ee = 0; ee < deg; ++ee) {
        int sidx = csrc[beg + ee];
        float e = als[sidx * 8 + h2] + aldv2;
        e = e > 0.f ? e : NEG_SLOPE * e;
        float alpha = __expf(e - m_h) * inv_s;
        float4 xv = *reinterpret_cast<const float4*>(xl + (size_t)sidx * 256 + (lane << 2));
        acc.x += alpha * xv.x; acc.y += alpha * xv.y;
        acc.z += alpha * xv.z; acc.w += alpha * xv.w;
    }
    float4 bv = *reinterpret_cast<const float4*>(bias + (lane << 2));
    acc.x += bv.x; acc.y += bv.y; acc.z += bv.z; acc.w += bv.w;
    acc.x = acc.x > 0.f ? acc.x : expm1f(acc.x);
    acc.y = acc.y > 0.f ? acc.y : expm1f(acc.y);
    acc.z = acc.z > 0.f ? acc.z : expm1f(acc.z);
    acc.w = acc.w > 0.f ? acc.w : expm1f(acc.w);
    *reinterpret_cast<float4*>(hout + (size_t)node * 256 + (lane << 2)) = acc;
}

// ---------------- layer 3: matvec + 1-channel aggregation ----------------

__global__ __launch_bounds__(256) void k_matvec(const float* __restrict__ h,
                                                const float* __restrict__ w,
                                                float* __restrict__ out, int n) {
    int node = (int)(((size_t)blockIdx.x * blockDim.x + threadIdx.x) >> 6);
    if (node >= n) return;
    int lane = threadIdx.x & 63;
    float4 hv = *reinterpret_cast<const float4*>(h + (size_t)node * 256 + (lane << 2));
    float4 wv = *reinterpret_cast<const float4*>(w + (lane << 2));
    float p = hv.x * wv.x + hv.y * wv.y + hv.z * wv.z + hv.w * wv.w;
#pragma unroll
    for (int off = 1; off < 64; off <<= 1) p += __shfl_xor(p, off);
    if (lane == 0) out[node] = p;
}

__global__ __launch_bounds__(256) void k_final(const float* __restrict__ xl3,
                                               const int* __restrict__ rowptr,
                                               const int* __restrict__ csrc,
                                               const float* __restrict__ as3,
                                               const float* __restrict__ ad3,
                                               const float* __restrict__ b3,
                                               float* __restrict__ out, int n) {
    int node = (int)(((size_t)blockIdx.x * blockDim.x + threadIdx.x) >> 6);
    if (node >= n) return;
    int lane = threadIdx.x & 63;
    int beg = rowptr[node];
    int deg = rowptr[node + 1] - beg;
    float a_s = as3[0], a_d = ad3[0], bb = b3[0];
    float dterm = a_d * xl3[node];
    float m = -1e30f, s = 0.f, w = 0.f;
    for (int ee = lane; ee < deg; ee += 64) {
        int sidx = csrc[beg + ee];
        float xs = xl3[sidx];
        float e = a_s * xs + dterm;
        e = e > 0.f ? e : NEG_SLOPE * e;
        float mn = fmaxf(m, e);
        float sc = __expf(m - mn);
        float ex = __expf(e - mn);
        s = s * sc + ex;
        w = w * sc + ex * xs;
        m = mn;
    }
#pragma unroll
    for (int off = 1; off < 64; off <<= 1) {
        float m2 = __shfl_xor(m, off);
        float s2 = __shfl_xor(s, off);
        float w2 = __shfl_xor(w, off);
        float mn = fmaxf(m, m2);
        float sc1 = __expf(m - mn), sc2 = __expf(m2 - mn);
        s = s * sc1 + s2 * sc2;
        w = w * sc1 + w2 * sc2;
        m = mn;
    }
    if (lane == 0) out[node] = w / (s + 1e-16f) + bb;
}

// ---------------- launcher ----------------

extern "C" void kernel_launch(void* const* d_in, const int* in_sizes, int n_in,
                              void* d_out, int out_size, void* d_ws, size_t ws_size,
                              hipStream_t stream) {
    const float* x   = (const float*)d_in[0];
    const int*   ei  = (const int*)d_in[1];
    const float* W0  = (const float*)d_in[2];
    const float* as0 = (const float*)d_in[3];
    const float* ad0 = (const float*)d_in[4];
    const float* b0  = (const float*)d_in[5];
    const float* W1  = (const float*)d_in[6];
    const float* as1 = (const float*)d_in[7];
    const float* ad1 = (const float*)d_in[8];
    const float* b1  = (const float*)d_in[9];
    const float* W2  = (const float*)d_in[10];
    const float* as2 = (const float*)d_in[11];
    const float* ad2 = (const float*)d_in[12];
    const float* b2  = (const float*)d_in[13];
    const float* W3  = (const float*)d_in[14];
    const float* as3 = (const float*)d_in[15];
    const float* ad3 = (const float*)d_in[16];
    const float* b3  = (const float*)d_in[17];

    int N  = in_sizes[0] / 64;        // 30000
    int E  = in_sizes[1] / 2;         // 480000
    int K0 = in_sizes[2] / 256;       // 64

    char* ws = (char*)d_ws;
    auto alloc = [&](size_t bytes) {
        char* p = ws;
        ws += (bytes + 255) & ~(size_t)255;
        return p;
    };
    int*   rowptr = (int*)alloc((size_t)(N + 1) * 4);
    int*   cursor = (int*)alloc((size_t)N * 4);
    int*   counts = (int*)alloc((size_t)N * 4);
    int*   csrc   = (int*)alloc((size_t)(E + N) * 4);
    float* xl     = (float*)alloc((size_t)N * 256 * 4);
    float* h      = (float*)alloc((size_t)N * 256 * 4);
    float* als    = (float*)alloc((size_t)N * 8 * 4);
    float* ald    = (float*)alloc((size_t)N * 8 * 4);
    float* xl3    = (float*)alloc((size_t)N * 4);

    hipMemsetAsync(cursor, 0, (size_t)N * 4, stream);
    k_init_counts<<<(N + 255) / 256, 256, 0, stream>>>(counts, N);
    k_hist<<<(E + 255) / 256, 256, 0, stream>>>(ei, E, counts);
    k_scan<<<1, 1024, 0, stream>>>(counts, rowptr, N);
    k_scatter<<<(E + N + 255) / 256, 256, 0, stream>>>(ei, E, N, rowptr, cursor, csrc);

    int nwb = (N + 3) / 4;  // one wave per node, 4 waves/block
    dim3 ggrid((N + 63) / 64, 4);

    // layer 0 (K=64)
    k_gemm<<<dim3((N + 63) / 64, 4), 256, 0, stream>>>(x, W0, xl, N, K0, 256);
    k_attn<<<nwb, 256, 0, stream>>>(xl, as0, ad0, als, ald, N);
    k_agg<<<nwb, 256, 0, stream>>>(xl, als, ald, rowptr, csrc, b0, h, N);
    // layer 1
    k_gemm<<<ggrid, 256, 0, stream>>>(h, W1, xl, N, 256, 256);
    k_attn<<<nwb, 256, 0, stream>>>(xl, as1, ad1, als, ald, N);
    k_agg<<<nwb, 256, 0, stream>>>(xl, als, ald, rowptr, csrc, b1, h, N);
    // layer 2
    k_gemm<<<ggrid, 256, 0, stream>>>(h, W2, xl, N, 256, 256);
    k_attn<<<nwb, 256, 0, stream>>>(xl, as2, ad2, als, ald, N);
    k_agg<<<nwb, 256, 0, stream>>>(xl, als, ald, rowptr, csrc, b2, h, N);
    // layer 3
    k_matvec<<<nwb, 256, 0, stream>>>(h, W3, xl3, N);
    k_final<<<nwb, 256, 0, stream>>>(xl3, rowptr, csrc, as3, ad3, b3, (float*)d_out, N);
}

// Round 2
// 351.264 us; speedup vs baseline: 1.5473x; 1.5473x over previous
//
#include <hip/hip_runtime.h>
#include <hip/hip_bf16.h>

#define NEG_SLOPE 0.2f

typedef __attribute__((ext_vector_type(8))) short bf16x8;
typedef __attribute__((ext_vector_type(4))) float f32x4;

__device__ __forceinline__ void gload_lds16(const void* g, void* l) {
    __builtin_amdgcn_global_load_lds((const __attribute__((address_space(1))) void*)g,
                                     (__attribute__((address_space(3))) void*)l,
                                     16, 0, 0);
}
__device__ __forceinline__ float bf2f(unsigned short u) {
    return __uint_as_float(((unsigned int)u) << 16);
}
__device__ __forceinline__ unsigned short f2bf(float f) {
    __hip_bfloat16 h = __float2bfloat16(f);
    return *reinterpret_cast<unsigned short*>(&h);
}

// ---------------- CSR build ----------------

__global__ void k_init_counts(int* counts, int n) {
    int i = blockIdx.x * blockDim.x + threadIdx.x;
    if (i < n) counts[i] = 1;  // self loop
}

__global__ void k_hist(const int* __restrict__ ei, int E, int* counts) {
    int i = blockIdx.x * blockDim.x + threadIdx.x;
    if (i < E) atomicAdd(&counts[ei[E + i]], 1);
}

// chunked scan: 1024 threads, each takes ceil(n/1024) contiguous elems
__global__ __launch_bounds__(1024) void k_scan(const int* __restrict__ counts,
                                               int* __restrict__ rowptr, int n) {
    __shared__ int wsum[16];
    __shared__ int wpre[16];
    int t = threadIdx.x;
    int chunk = (n + 1023) >> 10;
    int lo = t * chunk, hi = min(lo + chunk, n);
    if (lo > n) lo = n;
    if (hi < lo) hi = lo;
    int s = 0;
    for (int i = lo; i < hi; ++i) s += counts[i];
    int lane = t & 63, w = t >> 6;
    int v = s;
#pragma unroll
    for (int off = 1; off < 64; off <<= 1) {
        int u = __shfl_up(v, off);
        if (lane >= off) v += u;
    }
    if (lane == 63) wsum[w] = v;
    __syncthreads();
    if (w == 0 && lane < 16) {
        int x = wsum[lane];
#pragma unroll
        for (int off = 1; off < 16; off <<= 1) {
            int u = __shfl_up(x, off);
            if (lane >= off) x += u;
        }
        wpre[lane] = x - wsum[lane];
    }
    __syncthreads();
    int run = wpre[w] + v - s;  // exclusive prefix of this thread's chunk
    for (int i = lo; i < hi; ++i) { rowptr[i] = run; run += counts[i]; }
    if (t == 1023) rowptr[n] = run;
}

__global__ void k_scatter(const int* __restrict__ ei, int E, int n,
                          const int* __restrict__ rowptr, int* __restrict__ cursor,
                          int* __restrict__ csrc) {
    int i = blockIdx.x * blockDim.x + threadIdx.x;
    int tot = E + n;
    if (i >= tot) return;
    int s, d;
    if (i < E) { s = ei[i]; d = ei[E + i]; } else { s = i - E; d = s; }
    int pos = rowptr[d] + atomicAdd(&cursor[d], 1);
    csrc[pos] = s;
}

// ---------------- conversions ----------------

__global__ void k_cvtA(const float* __restrict__ x, __hip_bfloat16* __restrict__ xb,
                       int N, int K, int total) {
    int i = blockIdx.x * blockDim.x + threadIdx.x;
    if (i >= total) return;
    int r = i / K;
    xb[i] = __float2bfloat16(r < N ? x[i] : 0.f);
}

// Wt[c][k] = bf16(W[k][c])
__global__ void k_cvtWt(const float* __restrict__ W, __hip_bfloat16* __restrict__ Wt,
                        int K, int NC) {
    int i = blockIdx.x * blockDim.x + threadIdx.x;
    if (i >= K * NC) return;
    int c = i / K, k = i - c * K;
    Wt[i] = __float2bfloat16(W[(size_t)k * NC + c]);
}

// ---------------- bf16 MFMA GEMM: C[Mpad,256] = A[Mpad,K] @ Bt[256,K]^T ----------------
// BM=128, BN=128, BK=32, 4 waves (2x2), 4x4 16x16 frags/wave.

__global__ __launch_bounds__(256) void k_gemm_mfma(
    const __hip_bfloat16* __restrict__ A,   // [Mpad][K]
    const __hip_bfloat16* __restrict__ Bt,  // [NC][K] (W transposed)
    float* __restrict__ Cf,                 // [Mpad][NC] f32 out
    __hip_bfloat16* __restrict__ Cb,        // [Mpad][NC] bf16 out
    int K, int NC)
{
    __shared__ __hip_bfloat16 As[128 * 32];
    __shared__ __hip_bfloat16 Bs[128 * 32];
    int tid = threadIdx.x;
    int lane = tid & 63, w = tid >> 6;
    int wm = w >> 1, wn = w & 1;
    int rr = lane & 15, kg = lane >> 4;
    int bm = blockIdx.x * 128, bn = blockIdx.y * 128;

    f32x4 acc[4][4] = {};

    for (int k0 = 0; k0 < K; k0 += 32) {
        // stage: chunk c = s*256 + tid; row=c>>2, slot=c&3; swizzled k source
#pragma unroll
        for (int s = 0; s < 2; ++s) {
            int c = tid + s * 256;
            int r = c >> 2, sl = c & 3;
            int ksrc = k0 + 8 * (sl ^ ((r >> 1) & 3));
            char* dstA = ((char*)As) + s * 4096 + w * 1024;
            char* dstB = ((char*)Bs) + s * 4096 + w * 1024;
            gload_lds16(A + (size_t)(bm + r) * K + ksrc, dstA);
            gload_lds16(Bt + (size_t)(bn + r) * K + ksrc, dstB);
        }
        __syncthreads();
        bf16x8 af[4], bfr[4];
#pragma unroll
        for (int i = 0; i < 4; ++i) {
            int row = wm * 64 + i * 16 + rr;
            af[i] = *(const bf16x8*)((const char*)As + row * 64 + ((kg ^ ((row >> 1) & 3)) << 4));
        }
#pragma unroll
        for (int j = 0; j < 4; ++j) {
            int col = wn * 64 + j * 16 + rr;
            bfr[j] = *(const bf16x8*)((const char*)Bs + col * 64 + ((kg ^ ((col >> 1) & 3)) << 4));
        }
#pragma unroll
        for (int i = 0; i < 4; ++i)
#pragma unroll
            for (int j = 0; j < 4; ++j)
                acc[i][j] = __builtin_amdgcn_mfma_f32_16x16x32_bf16(af[i], bfr[j], acc[i][j], 0, 0, 0);
        __syncthreads();
    }
    // epilogue: C/D layout col=lane&15, row=(lane>>4)*4+q
#pragma unroll
    for (int i = 0; i < 4; ++i) {
#pragma unroll
        for (int j = 0; j < 4; ++j) {
            int col = bn + wn * 64 + j * 16 + rr;
#pragma unroll
            for (int q = 0; q < 4; ++q) {
                int row = bm + wm * 64 + i * 16 + kg * 4 + q;
                float v = acc[i][j][q];
                Cb[(size_t)row * NC + col] = __float2bfloat16(v);
                Cf[(size_t)row * NC + col] = v;
            }
        }
    }
}

// ---------------- attention coefficients from f32 xl ----------------

__global__ __launch_bounds__(256) void k_attn(const float* __restrict__ xl,
                                              const float* __restrict__ as_,
                                              const float* __restrict__ ad_,
                                              float* __restrict__ als,
                                              float* __restrict__ ald, int n) {
    int node = (int)(((size_t)blockIdx.x * blockDim.x + threadIdx.x) >> 6);
    if (node >= n) return;
    int lane = threadIdx.x & 63;
    float4 xv = *reinterpret_cast<const float4*>(xl + (size_t)node * 256 + (lane << 2));
    float4 sv = *reinterpret_cast<const float4*>(as_ + (lane << 2));
    float4 dv = *reinterpret_cast<const float4*>(ad_ + (lane << 2));
    float ps = xv.x * sv.x + xv.y * sv.y + xv.z * sv.z + xv.w * sv.w;
    float pd = xv.x * dv.x + xv.y * dv.y + xv.z * dv.z + xv.w * dv.w;
#pragma unroll
    for (int off = 1; off < 8; off <<= 1) {
        ps += __shfl_xor(ps, off);
        pd += __shfl_xor(pd, off);
    }
    if ((lane & 7) == 0) {
        als[node * 8 + (lane >> 3)] = ps;
        ald[node * 8 + (lane >> 3)] = pd;
    }
}

// ---------------- softmax + aggregation (bf16 gather, bf16 h out, ELU fused) ----------------

__global__ __launch_bounds__(256) void k_agg(const __hip_bfloat16* __restrict__ xlb,
                                             const float* __restrict__ als,
                                             const float* __restrict__ ald,
                                             const int* __restrict__ rowptr,
                                             const int* __restrict__ csrc,
                                             const float* __restrict__ bias,
                                             __hip_bfloat16* __restrict__ hb, int n) {
    int node = (int)(((size_t)blockIdx.x * blockDim.x + threadIdx.x) >> 6);
    if (node >= n) return;
    int lane = threadIdx.x & 63;
    int beg = rowptr[node];
    int deg = rowptr[node + 1] - beg;

    // sweep 1: online softmax stats, lane = 8*edge_slot + head
    int h1 = lane & 7;
    float aldv = ald[node * 8 + h1];
    float m = -1e30f, s = 0.f;
    for (int ee = lane >> 3; ee < deg; ee += 8) {
        int sidx = csrc[beg + ee];
        float e = als[sidx * 8 + h1] + aldv;
        e = e > 0.f ? e : NEG_SLOPE * e;
        float mn = fmaxf(m, e);
        s = s * __expf(m - mn) + __expf(e - mn);
        m = mn;
    }
#pragma unroll
    for (int off = 8; off < 64; off <<= 1) {
        float m2 = __shfl_xor(m, off);
        float s2 = __shfl_xor(s, off);
        float mn = fmaxf(m, m2);
        s = s * __expf(m - mn) + s2 * __expf(m2 - mn);
        m = mn;
    }
    // sweep 2: lane covers channels 4l..4l+3, head h2 = l>>3
    int h2 = lane >> 3;
    float m_h = __shfl(m, h2);
    float inv_s = 1.f / (__shfl(s, h2) + 1e-16f);
    float aldv2 = ald[node * 8 + h2];
    float4 a0 = make_float4(0.f, 0.f, 0.f, 0.f);
    float4 a1 = make_float4(0.f, 0.f, 0.f, 0.f);
    int ee = 0;
    for (; ee + 2 <= deg; ee += 2) {
        int s0 = csrc[beg + ee], s1 = csrc[beg + ee + 1];
        float e0 = als[s0 * 8 + h2] + aldv2;
        float e1 = als[s1 * 8 + h2] + aldv2;
        e0 = e0 > 0.f ? e0 : NEG_SLOPE * e0;
        e1 = e1 > 0.f ? e1 : NEG_SLOPE * e1;
        float al0 = __expf(e0 - m_h) * inv_s;
        float al1 = __expf(e1 - m_h) * inv_s;
        ushort4 x0 = *(const ushort4*)(xlb + (size_t)s0 * 256 + (lane << 2));
        ushort4 x1 = *(const ushort4*)(xlb + (size_t)s1 * 256 + (lane << 2));
        a0.x += al0 * bf2f(x0.x); a0.y += al0 * bf2f(x0.y);
        a0.z += al0 * bf2f(x0.z); a0.w += al0 * bf2f(x0.w);
        a1.x += al1 * bf2f(x1.x); a1.y += al1 * bf2f(x1.y);
        a1.z += al1 * bf2f(x1.z); a1.w += al1 * bf2f(x1.w);
    }
    if (ee < deg) {
        int s0 = csrc[beg + ee];
        float e0 = als[s0 * 8 + h2] + aldv2;
        e0 = e0 > 0.f ? e0 : NEG_SLOPE * e0;
        float al0 = __expf(e0 - m_h) * inv_s;
        ushort4 x0 = *(const ushort4*)(xlb + (size_t)s0 * 256 + (lane << 2));
        a0.x += al0 * bf2f(x0.x); a0.y += al0 * bf2f(x0.y);
        a0.z += al0 * bf2f(x0.z); a0.w += al0 * bf2f(x0.w);
    }
    float4 bv = *reinterpret_cast<const float4*>(bias + (lane << 2));
    float o0 = a0.x + a1.x + bv.x;
    float o1 = a0.y + a1.y + bv.y;
    float o2 = a0.z + a1.z + bv.z;
    float o3 = a0.w + a1.w + bv.w;
    o0 = o0 > 0.f ? o0 : expm1f(o0);
    o1 = o1 > 0.f ? o1 : expm1f(o1);
    o2 = o2 > 0.f ? o2 : expm1f(o2);
    o3 = o3 > 0.f ? o3 : expm1f(o3);
    ushort4 o;
    o.x = f2bf(o0); o.y = f2bf(o1); o.z = f2bf(o2); o.w = f2bf(o3);
    *(ushort4*)(hb + (size_t)node * 256 + (lane << 2)) = o;
}

// ---------------- layer 3 ----------------

__global__ __launch_bounds__(256) void k_matvec(const __hip_bfloat16* __restrict__ hb,
                                                const float* __restrict__ w,
                                                float* __restrict__ out, int n) {
    int node = (int)(((size_t)blockIdx.x * blockDim.x + threadIdx.x) >> 6);
    if (node >= n) return;
    int lane = threadIdx.x & 63;
    ushort4 hv = *(const ushort4*)(hb + (size_t)node * 256 + (lane << 2));
    float4 wv = *reinterpret_cast<const float4*>(w + (lane << 2));
    float p = bf2f(hv.x) * wv.x + bf2f(hv.y) * wv.y + bf2f(hv.z) * wv.z + bf2f(hv.w) * wv.w;
#pragma unroll
    for (int off = 1; off < 64; off <<= 1) p += __shfl_xor(p, off);
    if (lane == 0) out[node] = p;
}

__global__ __launch_bounds__(256) void k_final(const float* __restrict__ xl3,
                                               const int* __restrict__ rowptr,
                                               const int* __restrict__ csrc,
                                               const float* __restrict__ as3,
                                               const float* __restrict__ ad3,
                                               const float* __restrict__ b3,
                                               float* __restrict__ out, int n) {
    int node = (int)(((size_t)blockIdx.x * blockDim.x + threadIdx.x) >> 6);
    if (node >= n) return;
    int lane = threadIdx.x & 63;
    int beg = rowptr[node];
    int deg = rowptr[node + 1] - beg;
    float a_s = as3[0], a_d = ad3[0], bb = b3[0];
    float dterm = a_d * xl3[node];
    float m = -1e30f, s = 0.f, wv = 0.f;
    for (int ee = lane; ee < deg; ee += 64) {
        int sidx = csrc[beg + ee];
        float xs = xl3[sidx];
        float e = a_s * xs + dterm;
        e = e > 0.f ? e : NEG_SLOPE * e;
        float mn = fmaxf(m, e);
        float sc = __expf(m - mn);
        float ex = __expf(e - mn);
        s = s * sc + ex;
        wv = wv * sc + ex * xs;
        m = mn;
    }
#pragma unroll
    for (int off = 1; off < 64; off <<= 1) {
        float m2 = __shfl_xor(m, off);
        float s2 = __shfl_xor(s, off);
        float w2 = __shfl_xor(wv, off);
        float mn = fmaxf(m, m2);
        float sc1 = __expf(m - mn), sc2 = __expf(m2 - mn);
        s = s * sc1 + s2 * sc2;
        wv = wv * sc1 + w2 * sc2;
        m = mn;
    }
    if (lane == 0) out[node] = wv / (s + 1e-16f) + bb;
}

// ---------------- launcher ----------------

extern "C" void kernel_launch(void* const* d_in, const int* in_sizes, int n_in,
                              void* d_out, int out_size, void* d_ws, size_t ws_size,
                              hipStream_t stream) {
    const float* x   = (const float*)d_in[0];
    const int*   ei  = (const int*)d_in[1];
    const float* W0  = (const float*)d_in[2];
    const float* as0 = (const float*)d_in[3];
    const float* ad0 = (const float*)d_in[4];
    const float* b0  = (const float*)d_in[5];
    const float* W1  = (const float*)d_in[6];
    const float* as1 = (const float*)d_in[7];
    const float* ad1 = (const float*)d_in[8];
    const float* b1  = (const float*)d_in[9];
    const float* W2  = (const float*)d_in[10];
    const float* as2 = (const float*)d_in[11];
    const float* ad2 = (const float*)d_in[12];
    const float* b2  = (const float*)d_in[13];
    const float* W3  = (const float*)d_in[14];
    const float* as3 = (const float*)d_in[15];
    const float* ad3 = (const float*)d_in[16];
    const float* b3  = (const float*)d_in[17];

    int N    = in_sizes[0] / 64;   // 30000
    int E    = in_sizes[1] / 2;    // 480000
    int K0   = in_sizes[2] / 256;  // 64
    int Npad = (N + 127) & ~127;   // 30080

    char* ws = (char*)d_ws;
    auto alloc = [&](size_t bytes) {
        char* p = ws;
        ws += (bytes + 255) & ~(size_t)255;
        return p;
    };
    int*   rowptr = (int*)alloc((size_t)(N + 1) * 4);
    int*   cursor = (int*)alloc((size_t)N * 4);
    int*   counts = (int*)alloc((size_t)N * 4);
    int*   csrc   = (int*)alloc((size_t)(E + N) * 4);
    __hip_bfloat16* xb  = (__hip_bfloat16*)alloc((size_t)Npad * K0 * 2);
    __hip_bfloat16* W0t = (__hip_bfloat16*)alloc((size_t)K0 * 256 * 2);
    __hip_bfloat16* W1t = (__hip_bfloat16*)alloc((size_t)256 * 256 * 2);
    __hip_bfloat16* W2t = (__hip_bfloat16*)alloc((size_t)256 * 256 * 2);
    float*          xlf = (float*)alloc((size_t)Npad * 256 * 4);
    __hip_bfloat16* xlb = (__hip_bfloat16*)alloc((size_t)Npad * 256 * 2);
    __hip_bfloat16* hb  = (__hip_bfloat16*)alloc((size_t)Npad * 256 * 2);
    float* als = (float*)alloc((size_t)N * 8 * 4);
    float* ald = (float*)alloc((size_t)N * 8 * 4);
    float* xl3 = (float*)alloc((size_t)N * 4);

    hipMemsetAsync(cursor, 0, (size_t)N * 4, stream);
    // zero pad rows of hb (xb pad handled inside k_cvtA)
    hipMemsetAsync(hb + (size_t)N * 256, 0, (size_t)(Npad - N) * 256 * 2, stream);

    // conversions
    int totA = Npad * K0;
    k_cvtA<<<(totA + 255) / 256, 256, 0, stream>>>(x, xb, N, K0, totA);
    k_cvtWt<<<(K0 * 256 + 255) / 256, 256, 0, stream>>>(W0, W0t, K0, 256);
    k_cvtWt<<<(256 * 256 + 255) / 256, 256, 0, stream>>>(W1, W1t, 256, 256);
    k_cvtWt<<<(256 * 256 + 255) / 256, 256, 0, stream>>>(W2, W2t, 256, 256);

    // CSR
    k_init_counts<<<(N + 255) / 256, 256, 0, stream>>>(counts, N);
    k_hist<<<(E + 255) / 256, 256, 0, stream>>>(ei, E, counts);
    k_scan<<<1, 1024, 0, stream>>>(counts, rowptr, N);
    k_scatter<<<(E + N + 255) / 256, 256, 0, stream>>>(ei, E, N, rowptr, cursor, csrc);

    int nwb = (N + 3) / 4;
    dim3 ggrid(Npad / 128, 2);

    // layer 0
    k_gemm_mfma<<<ggrid, 256, 0, stream>>>(xb, W0t, xlf, xlb, K0, 256);
    k_attn<<<nwb, 256, 0, stream>>>(xlf, as0, ad0, als, ald, N);
    k_agg<<<nwb, 256, 0, stream>>>(xlb, als, ald, rowptr, csrc, b0, hb, N);
    // layer 1
    k_gemm_mfma<<<ggrid, 256, 0, stream>>>(hb, W1t, xlf, xlb, 256, 256);
    k_attn<<<nwb, 256, 0, stream>>>(xlf, as1, ad1, als, ald, N);
    k_agg<<<nwb, 256, 0, stream>>>(xlb, als, ald, rowptr, csrc, b1, hb, N);
    // layer 2
    k_gemm_mfma<<<ggrid, 256, 0, stream>>>(hb, W2t, xlf, xlb, 256, 256);
    k_attn<<<nwb, 256, 0, stream>>>(xlf, as2, ad2, als, ald, N);
    k_agg<<<nwb, 256, 0, stream>>>(xlb, als, ald, rowptr, csrc, b2, hb, N);
    // layer 3
    k_matvec<<<nwb, 256, 0, stream>>>(hb, W3, xl3, N);
    k_final<<<nwb, 256, 0, stream>>>(xl3, rowptr, csrc, as3, ad3, b3, (float*)d_out, N);
}

// Round 3
// 309.139 us; speedup vs baseline: 1.7582x; 1.1363x over previous
//
#include <hip/hip_runtime.h>
#include <hip/hip_bf16.h>

#define NEG_SLOPE 0.2f

typedef __attribute__((ext_vector_type(8))) short bf16x8;
typedef __attribute__((ext_vector_type(4))) float f32x4;

__device__ __forceinline__ void gload_lds16(const void* g, void* l) {
    __builtin_amdgcn_global_load_lds((const __attribute__((address_space(1))) void*)g,
                                     (__attribute__((address_space(3))) void*)l,
                                     16, 0, 0);
}
__device__ __forceinline__ float bflo(unsigned int u) {
    return __uint_as_float(u << 16);
}
__device__ __forceinline__ float bfhi(unsigned int u) {
    return __uint_as_float(u & 0xffff0000u);
}
__device__ __forceinline__ unsigned short f2bf(float f) {
    __hip_bfloat16 h = __float2bfloat16(f);
    return *reinterpret_cast<unsigned short*>(&h);
}

// ---------------- CSR build ----------------

__global__ void k_hist(const int* __restrict__ ei, int E, int* counts) {
    int i = blockIdx.x * blockDim.x + threadIdx.x;
    if (i < E) atomicAdd(&counts[ei[E + i]], 1);
}

// chunked scan over (counts[i]+1) -> rowptr[0..n]; +1 = self loop
__global__ __launch_bounds__(1024) void k_scan(const int* __restrict__ counts,
                                               int* __restrict__ rowptr, int n) {
    __shared__ int wsum[16];
    __shared__ int wpre[16];
    int t = threadIdx.x;
    int chunk = (n + 1023) >> 10;
    int lo = t * chunk, hi = min(lo + chunk, n);
    if (lo > n) lo = n;
    if (hi < lo) hi = lo;
    int s = 0;
    for (int i = lo; i < hi; ++i) s += counts[i] + 1;
    int lane = t & 63, w = t >> 6;
    int v = s;
#pragma unroll
    for (int off = 1; off < 64; off <<= 1) {
        int u = __shfl_up(v, off);
        if (lane >= off) v += u;
    }
    if (lane == 63) wsum[w] = v;
    __syncthreads();
    if (w == 0 && lane < 16) {
        int x = wsum[lane];
#pragma unroll
        for (int off = 1; off < 16; off <<= 1) {
            int u = __shfl_up(x, off);
            if (lane >= off) x += u;
        }
        wpre[lane] = x - wsum[lane];
    }
    __syncthreads();
    int run = wpre[w] + v - s;
    for (int i = lo; i < hi; ++i) { rowptr[i] = run; run += counts[i] + 1; }
    if (t == 1023) rowptr[n] = run;
}

// self loop at slot rowptr[d]; edges at rowptr[d]+1+cursor
__global__ void k_scatter(const int* __restrict__ ei, int E, int n,
                          const int* __restrict__ rowptr, int* __restrict__ cursor,
                          int* __restrict__ csrc) {
    int i = blockIdx.x * blockDim.x + threadIdx.x;
    int tot = E + n;
    if (i >= tot) return;
    if (i >= E) {
        int d = i - E;
        csrc[rowptr[d]] = d;
    } else {
        int s = ei[i], d = ei[E + i];
        int pos = rowptr[d] + 1 + atomicAdd(&cursor[d], 1);
        csrc[pos] = s;
    }
}

// ---------------- fused conversions: xb pad-cast + 3 weight transposes ----------------

__global__ void k_prep(const float* __restrict__ x, const float* __restrict__ W0,
                       const float* __restrict__ W1, const float* __restrict__ W2,
                       __hip_bfloat16* __restrict__ xb, __hip_bfloat16* __restrict__ W0t,
                       __hip_bfloat16* __restrict__ W1t, __hip_bfloat16* __restrict__ W2t,
                       int N, int K0, int totA) {
    int i = blockIdx.x * blockDim.x + threadIdx.x;
    if (i < totA) {
        int r = i / K0;
        xb[i] = __float2bfloat16(r < N ? x[i] : 0.f);
        return;
    }
    i -= totA;
    if (i < K0 * 256) {
        int c = i / K0, k = i - c * K0;
        W0t[i] = __float2bfloat16(W0[k * 256 + c]);
        return;
    }
    i -= K0 * 256;
    if (i < 65536) {
        int c = i >> 8, k = i & 255;
        W1t[i] = __float2bfloat16(W1[k * 256 + c]);
        return;
    }
    i -= 65536;
    if (i < 65536) {
        int c = i >> 8, k = i & 255;
        W2t[i] = __float2bfloat16(W2[k * 256 + c]);
    }
}

// ---------------- bf16 MFMA GEMM: C[Mpad,256] = A[Mpad,K] @ Bt[256,K]^T ----------------

__global__ __launch_bounds__(256) void k_gemm_mfma(
    const __hip_bfloat16* __restrict__ A,   // [Mpad][K]
    const __hip_bfloat16* __restrict__ Bt,  // [NC][K]
    __hip_bfloat16* __restrict__ Cb,        // [Mpad][NC]
    int K, int NC)
{
    __shared__ __hip_bfloat16 As[128 * 32];
    __shared__ __hip_bfloat16 Bs[128 * 32];
    int tid = threadIdx.x;
    int lane = tid & 63, w = tid >> 6;
    int wm = w >> 1, wn = w & 1;
    int rr = lane & 15, kg = lane >> 4;
    int bm = blockIdx.x * 128, bn = blockIdx.y * 128;

    f32x4 acc[4][4] = {};

    for (int k0 = 0; k0 < K; k0 += 32) {
#pragma unroll
        for (int s = 0; s < 2; ++s) {
            int c = tid + s * 256;
            int r = c >> 2, sl = c & 3;
            int ksrc = k0 + 8 * (sl ^ ((r >> 1) & 3));
            char* dstA = ((char*)As) + s * 4096 + w * 1024;
            char* dstB = ((char*)Bs) + s * 4096 + w * 1024;
            gload_lds16(A + (size_t)(bm + r) * K + ksrc, dstA);
            gload_lds16(Bt + (size_t)(bn + r) * K + ksrc, dstB);
        }
        __syncthreads();
        bf16x8 af[4], bfr[4];
#pragma unroll
        for (int i = 0; i < 4; ++i) {
            int row = wm * 64 + i * 16 + rr;
            af[i] = *(const bf16x8*)((const char*)As + row * 64 + ((kg ^ ((row >> 1) & 3)) << 4));
        }
#pragma unroll
        for (int j = 0; j < 4; ++j) {
            int col = wn * 64 + j * 16 + rr;
            bfr[j] = *(const bf16x8*)((const char*)Bs + col * 64 + ((kg ^ ((col >> 1) & 3)) << 4));
        }
#pragma unroll
        for (int i = 0; i < 4; ++i)
#pragma unroll
            for (int j = 0; j < 4; ++j)
                acc[i][j] = __builtin_amdgcn_mfma_f32_16x16x32_bf16(af[i], bfr[j], acc[i][j], 0, 0, 0);
        __syncthreads();
    }
#pragma unroll
    for (int i = 0; i < 4; ++i) {
#pragma unroll
        for (int j = 0; j < 4; ++j) {
            int col = bn + wn * 64 + j * 16 + rr;
#pragma unroll
            for (int q = 0; q < 4; ++q) {
                int row = bm + wm * 64 + i * 16 + kg * 4 + q;
                Cb[(size_t)row * NC + col] = __float2bfloat16(acc[i][j][q]);
            }
        }
    }
}

// ---------------- attention coefficients from bf16 xl ----------------

__global__ __launch_bounds__(256) void k_attn(const __hip_bfloat16* __restrict__ xlb,
                                              const float* __restrict__ as_,
                                              const float* __restrict__ ad_,
                                              float* __restrict__ als,
                                              float* __restrict__ ald, int n) {
    int node = (int)(((size_t)blockIdx.x * blockDim.x + threadIdx.x) >> 6);
    if (node >= n) return;
    int lane = threadIdx.x & 63;
    uint2 xv = *(const uint2*)(xlb + (size_t)node * 256 + (lane << 2));
    float x0 = bflo(xv.x), x1 = bfhi(xv.x), x2 = bflo(xv.y), x3 = bfhi(xv.y);
    float4 sv = *reinterpret_cast<const float4*>(as_ + (lane << 2));
    float4 dv = *reinterpret_cast<const float4*>(ad_ + (lane << 2));
    float ps = x0 * sv.x + x1 * sv.y + x2 * sv.z + x3 * sv.w;
    float pd = x0 * dv.x + x1 * dv.y + x2 * dv.z + x3 * dv.w;
#pragma unroll
    for (int off = 1; off < 8; off <<= 1) {
        ps += __shfl_xor(ps, off);
        pd += __shfl_xor(pd, off);
    }
    if ((lane & 7) == 0) {
        als[node * 8 + (lane >> 3)] = ps;
        ald[node * 8 + (lane >> 3)] = pd;
    }
}

// ---------------- single-pass flash aggregation + fused ELU (+ optional matvec) --------
// stats mapping: lane = 8*slot + head (8 edges x 8 heads batched alpha)
// gather mapping: lanes 0-31 edge t, 32-63 edge t+1; 8 channels/lane

#define AGG_PAIR(TT)                                                                 \
    {                                                                                \
        float alpha = __shfl(aval, sh_alpha + ((TT) << 4));                          \
        int sidx = __shfl(sb, sh_sidx + ((TT) << 4));                                \
        const uint4* xp = (const uint4*)(xrow + ((size_t)sidx << 8));                \
        uint4 xv = *xp;                                                              \
        acc[0] += alpha * bflo(xv.x); acc[1] += alpha * bfhi(xv.x);                  \
        acc[2] += alpha * bflo(xv.y); acc[3] += alpha * bfhi(xv.y);                  \
        acc[4] += alpha * bflo(xv.z); acc[5] += alpha * bfhi(xv.z);                  \
        acc[6] += alpha * bflo(xv.w); acc[7] += alpha * bfhi(xv.w);                  \
    }

__global__ __launch_bounds__(256) void k_agg(const __hip_bfloat16* __restrict__ xlb,
                                             const float* __restrict__ als,
                                             const float* __restrict__ ald,
                                             const int* __restrict__ rowptr,
                                             const int* __restrict__ csrc,
                                             const float* __restrict__ bias,
                                             __hip_bfloat16* __restrict__ hb,
                                             const float* __restrict__ w3,
                                             float* __restrict__ xl3, int n) {
    int node = (int)(((size_t)blockIdx.x * blockDim.x + threadIdx.x) >> 6);
    if (node >= n) return;
    int lane = threadIdx.x & 63;
    int beg = rowptr[node];
    int deg = rowptr[node + 1] - beg;

    int h1 = lane & 7, slot = lane >> 3;
    int half = lane >> 5;
    int l5 = lane & 31;
    int h2 = l5 >> 2;      // head of this lane's channels
    int ch0 = l5 << 3;     // 8 channels per lane
    int sh_alpha = (half << 3) + h2;
    int sh_sidx = (half << 3);
    const __hip_bfloat16* xrow = xlb + ch0;

    float aldv = ald[node * 8 + h1];
    float m = -1e30f, s = 0.f;
    float acc[8] = {};

    for (int base = 0; base < deg; base += 8) {
        int idx = base + slot;
        int cidx = idx < deg ? idx : deg - 1;
        int sb = csrc[beg + cidx];
        float e = -1e30f;
        if (idx < deg) {
            e = als[sb * 8 + h1] + aldv;
            e = e > 0.f ? e : NEG_SLOPE * e;
        }
        float mc = fmaxf(e, __shfl_xor(e, 8));
        mc = fmaxf(mc, __shfl_xor(mc, 16));
        mc = fmaxf(mc, __shfl_xor(mc, 32));
        float mn = fmaxf(m, mc);
        float scale = __expf(m - mn);
        float aval = __expf(e - mn);      // 0 for invalid slots
        float csum = aval + __shfl_xor(aval, 8);
        csum += __shfl_xor(csum, 16);
        csum += __shfl_xor(csum, 32);
        s = s * scale + csum;
        m = mn;
        float sca = __shfl(scale, h2);
#pragma unroll
        for (int c = 0; c < 8; ++c) acc[c] *= sca;
        int nn = min(8, deg - base);
        int npair = (nn + 1) >> 1;
        if (npair == 4) {
            AGG_PAIR(0) AGG_PAIR(1) AGG_PAIR(2) AGG_PAIR(3)
        } else {
            for (int tt = 0; tt < npair; ++tt) AGG_PAIR(tt)
        }
    }
    // merge the two edge-halves
#pragma unroll
    for (int c = 0; c < 8; ++c) acc[c] += __shfl_xor(acc[c], 32);
    float inv = __shfl(1.f / (s + 1e-16f), h2);
    float o[8];
    float4 bv0 = *reinterpret_cast<const float4*>(bias + ch0);
    float4 bv1 = *reinterpret_cast<const float4*>(bias + ch0 + 4);
    o[0] = acc[0] * inv + bv0.x; o[1] = acc[1] * inv + bv0.y;
    o[2] = acc[2] * inv + bv0.z; o[3] = acc[3] * inv + bv0.w;
    o[4] = acc[4] * inv + bv1.x; o[5] = acc[5] * inv + bv1.y;
    o[6] = acc[6] * inv + bv1.z; o[7] = acc[7] * inv + bv1.w;
#pragma unroll
    for (int c = 0; c < 8; ++c) o[c] = o[c] > 0.f ? o[c] : expm1f(o[c]);

    if (w3) {
        // fused layer-3 matvec: xl3[node] = dot(h, w3)
        float p = 0.f;
        if (half == 0) {
#pragma unroll
            for (int c = 0; c < 8; ++c) p += o[c] * w3[ch0 + c];
        }
#pragma unroll
        for (int off = 1; off < 64; off <<= 1) p += __shfl_xor(p, off);
        if (lane == 0) xl3[node] = p;
    } else if (half == 0) {
        uint4 ov;
        ov.x = (unsigned)f2bf(o[0]) | ((unsigned)f2bf(o[1]) << 16);
        ov.y = (unsigned)f2bf(o[2]) | ((unsigned)f2bf(o[3]) << 16);
        ov.z = (unsigned)f2bf(o[4]) | ((unsigned)f2bf(o[5]) << 16);
        ov.w = (unsigned)f2bf(o[6]) | ((unsigned)f2bf(o[7]) << 16);
        *(uint4*)(hb + (size_t)node * 256 + ch0) = ov;
    }
}

// ---------------- layer 3 final ----------------

__global__ __launch_bounds__(256) void k_final(const float* __restrict__ xl3,
                                               const int* __restrict__ rowptr,
                                               const int* __restrict__ csrc,
                                               const float* __restrict__ as3,
                                               const float* __restrict__ ad3,
                                               const float* __restrict__ b3,
                                               float* __restrict__ out, int n) {
    int node = (int)(((size_t)blockIdx.x * blockDim.x + threadIdx.x) >> 6);
    if (node >= n) return;
    int lane = threadIdx.x & 63;
    int beg = rowptr[node];
    int deg = rowptr[node + 1] - beg;
    float a_s = as3[0], a_d = ad3[0], bb = b3[0];
    float dterm = a_d * xl3[node];
    float m = -1e30f, s = 0.f, wv = 0.f;
    for (int ee = lane; ee < deg; ee += 64) {
        int sidx = csrc[beg + ee];
        float xs = xl3[sidx];
        float e = a_s * xs + dterm;
        e = e > 0.f ? e : NEG_SLOPE * e;
        float mn = fmaxf(m, e);
        float sc = __expf(m - mn);
        float ex = __expf(e - mn);
        s = s * sc + ex;
        wv = wv * sc + ex * xs;
        m = mn;
    }
#pragma unroll
    for (int off = 1; off < 64; off <<= 1) {
        float m2 = __shfl_xor(m, off);
        float s2 = __shfl_xor(s, off);
        float w2 = __shfl_xor(wv, off);
        float mn = fmaxf(m, m2);
        float sc1 = __expf(m - mn), sc2 = __expf(m2 - mn);
        s = s * sc1 + s2 * sc2;
        wv = wv * sc1 + w2 * sc2;
        m = mn;
    }
    if (lane == 0) out[node] = wv / (s + 1e-16f) + bb;
}

// ---------------- launcher ----------------

extern "C" void kernel_launch(void* const* d_in, const int* in_sizes, int n_in,
                              void* d_out, int out_size, void* d_ws, size_t ws_size,
                              hipStream_t stream) {
    const float* x   = (const float*)d_in[0];
    const int*   ei  = (const int*)d_in[1];
    const float* W0  = (const float*)d_in[2];
    const float* as0 = (const float*)d_in[3];
    const float* ad0 = (const float*)d_in[4];
    const float* b0  = (const float*)d_in[5];
    const float* W1  = (const float*)d_in[6];
    const float* as1 = (const float*)d_in[7];
    const float* ad1 = (const float*)d_in[8];
    const float* b1  = (const float*)d_in[9];
    const float* W2  = (const float*)d_in[10];
    const float* as2 = (const float*)d_in[11];
    const float* ad2 = (const float*)d_in[12];
    const float* b2  = (const float*)d_in[13];
    const float* W3  = (const float*)d_in[14];
    const float* as3 = (const float*)d_in[15];
    const float* ad3 = (const float*)d_in[16];
    const float* b3  = (const float*)d_in[17];

    int N    = in_sizes[0] / 64;   // 30000
    int E    = in_sizes[1] / 2;    // 480000
    int K0   = in_sizes[2] / 256;  // 64
    int Npad = (N + 127) & ~127;   // 30080

    char* ws = (char*)d_ws;
    auto alloc = [&](size_t bytes) {
        char* p = ws;
        ws += (bytes + 255) & ~(size_t)255;
        return p;
    };
    int* rowptr = (int*)alloc((size_t)(N + 1) * 4);
    int* cc     = (int*)alloc((size_t)2 * N * 4);  // cursor | counts
    int* cursor = cc;
    int* counts = cc + N;
    int* csrc   = (int*)alloc((size_t)(E + N) * 4);
    __hip_bfloat16* xb  = (__hip_bfloat16*)alloc((size_t)Npad * K0 * 2);
    __hip_bfloat16* W0t = (__hip_bfloat16*)alloc((size_t)K0 * 256 * 2);
    __hip_bfloat16* W1t = (__hip_bfloat16*)alloc((size_t)256 * 256 * 2);
    __hip_bfloat16* W2t = (__hip_bfloat16*)alloc((size_t)256 * 256 * 2);
    __hip_bfloat16* xlb = (__hip_bfloat16*)alloc((size_t)Npad * 256 * 2);
    __hip_bfloat16* hb  = (__hip_bfloat16*)alloc((size_t)Npad * 256 * 2);
    float* als = (float*)alloc((size_t)N * 8 * 4);
    float* ald = (float*)alloc((size_t)N * 8 * 4);
    float* xl3 = (float*)alloc((size_t)N * 4);

    hipMemsetAsync(cc, 0, (size_t)2 * N * 4, stream);
    hipMemsetAsync(hb + (size_t)N * 256, 0, (size_t)(Npad - N) * 256 * 2, stream);

    int totA = Npad * K0;
    int totPrep = totA + K0 * 256 + 65536 + 65536;
    k_prep<<<(totPrep + 255) / 256, 256, 0, stream>>>(x, W0, W1, W2, xb, W0t, W1t, W2t,
                                                      N, K0, totA);
    k_hist<<<(E + 255) / 256, 256, 0, stream>>>(ei, E, counts);
    k_scan<<<1, 1024, 0, stream>>>(counts, rowptr, N);
    k_scatter<<<(E + N + 255) / 256, 256, 0, stream>>>(ei, E, N, rowptr, cursor, csrc);

    int nwb = (N + 3) / 4;
    dim3 ggrid(Npad / 128, 2);

    // layer 0
    k_gemm_mfma<<<ggrid, 256, 0, stream>>>(xb, W0t, xlb, K0, 256);
    k_attn<<<nwb, 256, 0, stream>>>(xlb, as0, ad0, als, ald, N);
    k_agg<<<nwb, 256, 0, stream>>>(xlb, als, ald, rowptr, csrc, b0, hb, nullptr, nullptr, N);
    // layer 1
    k_gemm_mfma<<<ggrid, 256, 0, stream>>>(hb, W1t, xlb, 256, 256);
    k_attn<<<nwb, 256, 0, stream>>>(xlb, as1, ad1, als, ald, N);
    k_agg<<<nwb, 256, 0, stream>>>(xlb, als, ald, rowptr, csrc, b1, hb, nullptr, nullptr, N);
    // layer 2 (+ fused layer-3 matvec)
    k_gemm_mfma<<<ggrid, 256, 0, stream>>>(hb, W2t, xlb, 256, 256);
    k_attn<<<nwb, 256, 0, stream>>>(xlb, as2, ad2, als, ald, N);
    k_agg<<<nwb, 256, 0, stream>>>(xlb, als, ald, rowptr, csrc, b2, hb, W3, xl3, N);
    // layer 3
    k_final<<<nwb, 256, 0, stream>>>(xl3, rowptr, csrc, as3, ad3, b3, (float*)d_out, N);
}